// Round 14
// baseline (58.096 us; speedup 1.0000x reference)
//
#include <hip/hip_runtime.h>
#include <hip/hip_bf16.h>

typedef float f32x4 __attribute__((ext_vector_type(4)));
typedef float f32x16 __attribute__((ext_vector_type(16)));
typedef short s16x8 __attribute__((ext_vector_type(8)));
typedef unsigned int u32x4 __attribute__((ext_vector_type(4)));

__device__ __forceinline__ unsigned cvtpk(float lo, float hi) {
    unsigned r;
    asm("v_cvt_pk_bf16_f32 %0, %1, %2" : "=v"(r) : "v"(lo), "v"(hi));
    return r;
}
// v_permlane32_swap_b32: x <- {x_lo, y_lo}, y <- {x_hi, y_hi}
__device__ __forceinline__ void swap32(unsigned &x, unsigned &y) {
    asm("v_permlane32_swap_b32 %0, %1" : "+v"(x), "+v"(y));
}
// exact bf16->f32 of packed halves
__device__ __forceinline__ float bflo(unsigned q) { return __builtin_bit_cast(float, q << 16); }
__device__ __forceinline__ float bfhi(unsigned q) { return __builtin_bit_cast(float, q & 0xFFFF0000u); }

// Kernel 1: xa[a][k] = b1[k] + sum_d x[a][d]*W1[d][k];  yb[b][k] = sum_d y[b][d]*W1[128+d][k]
__global__ __launch_bounds__(128) void precompute_kernel(
    const float* __restrict__ x, const float* __restrict__ y,
    const float* __restrict__ W1, const float* __restrict__ b1,
    float* __restrict__ xa, float* __restrict__ yb)
{
    __shared__ float rows[8][128];
    const int bid = blockIdx.x;
    const int k = threadIdx.x;
    const bool is_x = bid < 128;
    const int r0 = (is_x ? bid : bid - 128) * 8;
    const float* src = (is_x ? x : y) + (size_t)r0 * 128;
    const float* w = is_x ? W1 : (W1 + 128 * 128);
#pragma unroll
    for (int r = 0; r < 8; ++r) rows[r][k] = src[r * 128 + k];
    __syncthreads();
    float acc[8];
    const float bias = is_x ? b1[k] : 0.0f;
#pragma unroll
    for (int r = 0; r < 8; ++r) acc[r] = bias;
    for (int d = 0; d < 128; ++d) {
        float wv = w[d * 128 + k];
#pragma unroll
        for (int r = 0; r < 8; ++r) acc[r] = fmaf(rows[r][d], wv, acc[r]);
    }
    float* dst = (is_x ? xa : yb) + (size_t)r0 * 128 + k;
#pragma unroll
    for (int r = 0; r < 8; ++r) dst[r * 128] = acc[r];
}

// Kernel 2: fused pairwise MLP, register-lean build for 4 waves/SIMD:
// W2/W3/biases in LDS (r8-validated tables), y packed to bf16 in registers
// (32 regs), single-row loop, no scheduling hints.
// Grid 1024 x 256. a_chunk = bid>>3 (8 a's via LDS), wave b-group = (bid&7)*4+wave.
__global__ __launch_bounds__(256, 4) void fused_kernel(
    const float* __restrict__ xa, const float* __restrict__ yb,
    const float* __restrict__ W2, const float* __restrict__ b2,
    const float* __restrict__ W3, const float* __restrict__ b3,
    const float* __restrict__ W4, const float* __restrict__ b4,
    float* __restrict__ out)
{
    __shared__ float xa_lds[8 * 128];                         // 4 KB
    __shared__ __align__(16) short w2_lds[2 * 8 * 64 * 8];    // 16 KB: [mt][s][lane][8]
    __shared__ __align__(16) short w3_lds[4 * 64 * 8];        // 4 KB:  [s][lane][8]
    __shared__ __align__(64) float b2_lds[64];                // [mt][half][16] C-layout
    __shared__ __align__(64) float b3_lds[32];                // [half][16] C-layout (r>=4 zero)

    const int tid = threadIdx.x;
    const int bid = blockIdx.x;
    const int a_chunk = bid >> 3;        // 0..127, 8 a's each
    const int bq = bid & 7;
    const int wave = tid >> 6;
    const int lane = tid & 63;
    const int half = lane >> 5;
    const int m = lane & 31;
    const int bg = bq * 4 + wave;        // 0..31

    // ---- stage xa tile (8 rows x 128 f32 = 4 KB) ----
    {
        const f32x4* xsrc = (const f32x4*)(xa + (size_t)a_chunk * 8 * 128);
        ((f32x4*)xa_lds)[tid] = xsrc[tid];
    }
    // ---- W2 fragment table (r8-validated): (mt,s,l)[j] = bf16(W2[(s*16+(l>>5)*8+j)*64 + mt*32 + (l&31)])
#pragma unroll
    for (int k = 0; k < 4; ++k) {
        int e = tid + 256 * k;
        int l = e & 63, s = (e >> 6) & 7, mt = e >> 9;
        int col = mt * 32 + (l & 31);
        int krow = s * 16 + (l >> 5) * 8;
        u32x4 q;
#pragma unroll
        for (int jj = 0; jj < 4; ++jj)
            q[jj] = cvtpk(W2[(krow + 2 * jj) * 64 + col], W2[(krow + 2 * jj + 1) * 64 + col]);
        *(u32x4*)&w2_lds[e * 8] = q;
    }
    // ---- W3 fragment table (M padded 8->32), r8-validated ----
    {
        int l = tid & 63, s = tid >> 6;
        int row = l & 31;
        int krow = s * 16 + (l >> 5) * 8;
        u32x4 q;
#pragma unroll
        for (int jj = 0; jj < 4; ++jj) {
            float lo = (row < 8) ? W3[(krow + 2 * jj) * 8 + row] : 0.f;
            float hi = (row < 8) ? W3[(krow + 2 * jj + 1) * 8 + row] : 0.f;
            q[jj] = cvtpk(lo, hi);
        }
        *(u32x4*)&w3_lds[tid * 8] = q;
    }
    // ---- bias C-init tables (r8-validated) ----
    if (tid < 64)
        b2_lds[tid] = b2[(tid & 3) + 8 * ((tid >> 2) & 3) + 4 * ((tid >> 4) & 1) + 32 * (tid >> 5)];
    if (tid < 32)
        b3_lds[tid] = ((tid & 15) < 4) ? b3[(tid & 3) + 4 * (tid >> 4)] : 0.f;

    // ---- y row packed to bf16 in B-fragment order: ybf[s] covers k = s*16+half*8 .. +7 ----
    u32x4 ybf[8];
    {
        const float* yrow = yb + (size_t)(bg * 32 + m) * 128 + half * 8;
#pragma unroll
        for (int s = 0; s < 8; ++s) {
            f32x4 y0 = *(const f32x4*)&yrow[s * 16];
            f32x4 y1 = *(const f32x4*)&yrow[s * 16 + 4];
            ybf[s].x = cvtpk(y0.x, y0.y);
            ybf[s].y = cvtpk(y0.z, y0.w);
            ybf[s].z = cvtpk(y1.x, y1.y);
            ybf[s].w = cvtpk(y1.z, y1.w);
        }
    }
    float w4v[4];
#pragma unroll
    for (int j = 0; j < 4; ++j) w4v[j] = W4[j + 4 * half];
    const float b4s = b4[0];

    __syncthreads();

    const short* w2p = &w2_lds[lane * 8];
    const short* w3p = &w3_lds[lane * 8];
    float* outp = out + (size_t)(a_chunk * 8) * 1024 + bg * 32 + m;

    for (int ai = 0; ai < 8; ++ai) {
        const float* xr = &xa_lds[ai * 128 + half * 8];
        const f32x16 cb0 = *(const f32x16*)&b2_lds[half * 16];
        const f32x16 cb1 = *(const f32x16*)&b2_lds[32 + half * 16];
        f32x16 c20, c21;
#pragma unroll
        for (int s = 0; s < 8; ++s) {
            // layer-1 B-fragment: f32 x (LDS broadcast) + f32(bf16 y) -> relu -> bf16
            f32x4 x0 = *(const f32x4*)&xr[s * 16];
            f32x4 x1 = *(const f32x4*)&xr[s * 16 + 4];
            u32x4 yq = ybf[s];
            u32x4 q;
            q.x = cvtpk(fmaxf(x0.x + bflo(yq.x), 0.f), fmaxf(x0.y + bfhi(yq.x), 0.f));
            q.y = cvtpk(fmaxf(x0.z + bflo(yq.y), 0.f), fmaxf(x0.w + bfhi(yq.y), 0.f));
            q.z = cvtpk(fmaxf(x1.x + bflo(yq.z), 0.f), fmaxf(x1.y + bfhi(yq.z), 0.f));
            q.w = cvtpk(fmaxf(x1.z + bflo(yq.w), 0.f), fmaxf(x1.w + bfhi(yq.w), 0.f));
            s16x8 bfrag = __builtin_bit_cast(s16x8, q);
            s16x8 wf0 = *(const s16x8*)(w2p + s * 512);          // mt0 frag (LDS)
            s16x8 wf1 = *(const s16x8*)(w2p + (8 + s) * 512);    // mt1 frag (LDS)
            if (s == 0) {
                c20 = __builtin_amdgcn_mfma_f32_32x32x16_bf16(wf0, bfrag, cb0, 0, 0, 0);
                c21 = __builtin_amdgcn_mfma_f32_32x32x16_bf16(wf1, bfrag, cb1, 0, 0, 0);
            } else {
                c20 = __builtin_amdgcn_mfma_f32_32x32x16_bf16(wf0, bfrag, c20, 0, 0, 0);
                c21 = __builtin_amdgcn_mfma_f32_32x32x16_bf16(wf1, bfrag, c21, 0, 0, 0);
            }
        }

        // relu(h2) pack; P covers features mt0, Q mt1
        unsigned P[8], Q[8];
#pragma unroll
        for (int i = 0; i < 8; ++i) {
            P[i] = cvtpk(fmaxf(c20[2 * i], 0.f), fmaxf(c20[2 * i + 1], 0.f));
            Q[i] = cvtpk(fmaxf(c21[2 * i], 0.f), fmaxf(c21[2 * i + 1], 0.f));
        }
        // C-layout -> layer-3 B-fragments (validated r1/r3/r5)
        s16x8 bf3[4];
        {
            unsigned w0 = P[0], w2 = P[2]; swap32(w0, w2);
            unsigned w1 = P[1], w3 = P[3]; swap32(w1, w3);
            u32x4 t; t.x = w0; t.y = w1; t.z = w2; t.w = w3;
            bf3[0] = __builtin_bit_cast(s16x8, t);
            unsigned v0 = P[4], v2 = P[6]; swap32(v0, v2);
            unsigned v1 = P[5], v3 = P[7]; swap32(v1, v3);
            u32x4 u; u.x = v0; u.y = v1; u.z = v2; u.w = v3;
            bf3[1] = __builtin_bit_cast(s16x8, u);
            unsigned a0 = Q[0], a2 = Q[2]; swap32(a0, a2);
            unsigned a1 = Q[1], a3 = Q[3]; swap32(a1, a3);
            u32x4 t2; t2.x = a0; t2.y = a1; t2.z = a2; t2.w = a3;
            bf3[2] = __builtin_bit_cast(s16x8, t2);
            unsigned e0 = Q[4], e2 = Q[6]; swap32(e0, e2);
            unsigned e1 = Q[5], e3 = Q[7]; swap32(e1, e3);
            u32x4 u2; u2.x = e0; u2.y = e1; u2.z = e2; u2.w = e3;
            bf3[3] = __builtin_bit_cast(s16x8, u2);
        }

        // Layer3: b3 C-init + W3 frags from LDS (r8-validated)
        f32x16 c3 = __builtin_amdgcn_mfma_f32_32x32x16_bf16(
            *(const s16x8*)(w3p + 0 * 512), bf3[0],
            *(const f32x16*)&b3_lds[half * 16], 0, 0, 0);
#pragma unroll
        for (int s = 1; s < 4; ++s)
            c3 = __builtin_amdgcn_mfma_f32_32x32x16_bf16(
                *(const s16x8*)(w3p + s * 512), bf3[s], c3, 0, 0, 0);

        // layer4: each lane has 4 of its pair's 8 h3 features (other 4 in lane^32)
        float p = fmaxf(c3[0], 0.f) * w4v[0] + fmaxf(c3[1], 0.f) * w4v[1]
                + fmaxf(c3[2], 0.f) * w4v[2] + fmaxf(c3[3], 0.f) * w4v[3];
        unsigned pu = __builtin_bit_cast(unsigned, p);
        unsigned pv = pu;
        asm("" : "+v"(pv));
        swap32(pu, pv);
        float r = __builtin_bit_cast(float, pu) + __builtin_bit_cast(float, pv) + b4s;
        if (half == 0)
            outp[(size_t)ai * 1024] = r;
    }
}

extern "C" void kernel_launch(void* const* d_in, const int* in_sizes, int n_in,
                              void* d_out, int out_size, void* d_ws, size_t ws_size,
                              hipStream_t stream) {
    const float* x  = (const float*)d_in[0];
    const float* y  = (const float*)d_in[1];
    const float* W1 = (const float*)d_in[2];
    const float* b1 = (const float*)d_in[3];
    const float* W2 = (const float*)d_in[4];
    const float* b2 = (const float*)d_in[5];
    const float* W3 = (const float*)d_in[6];
    const float* b3 = (const float*)d_in[7];
    const float* W4 = (const float*)d_in[8];
    const float* b4 = (const float*)d_in[9];
    float* out = (float*)d_out;

    float* xa = (float*)d_ws;              // 1024*128 f32
    float* yb = xa + 1024 * 128;           // 1024*128 f32

    precompute_kernel<<<dim3(256), dim3(128), 0, stream>>>(x, y, W1, b1, xa, yb);
    fused_kernel<<<dim3(1024), dim3(256), 0, stream>>>(xa, yb, W2, b2, W3, b3, W4, b4, out);
}

// Round 15
// 38.087 us; speedup vs baseline: 1.5254x; 1.5254x over previous
//
#include <hip/hip_runtime.h>
#include <hip/hip_bf16.h>

typedef float f32x4 __attribute__((ext_vector_type(4)));
typedef float f32x16 __attribute__((ext_vector_type(16)));
typedef short s16x8 __attribute__((ext_vector_type(8)));
typedef unsigned int u32x4 __attribute__((ext_vector_type(4)));

__device__ __forceinline__ short f2bf(float v) {
    __hip_bfloat16 h = __float2bfloat16(v);
    return __builtin_bit_cast(short, h);
}
__device__ __forceinline__ unsigned cvtpk(float lo, float hi) {
    unsigned r;
    asm("v_cvt_pk_bf16_f32 %0, %1, %2" : "=v"(r) : "v"(lo), "v"(hi));
    return r;
}
// v_permlane32_swap_b32: x <- {x_lo, y_lo}, y <- {x_hi, y_hi}
__device__ __forceinline__ void swap32(unsigned &x, unsigned &y) {
    asm("v_permlane32_swap_b32 %0, %1" : "+v"(x), "+v"(y));
}

// Kernel 1: xa[a][k] = b1[k] + sum_d x[a][d]*W1[d][k];  yb[b][k] = sum_d y[b][d]*W1[128+d][k]
// 512 blocks x 128 threads, 4 rows each (fills all CUs).
__global__ __launch_bounds__(128) void precompute_kernel(
    const float* __restrict__ x, const float* __restrict__ y,
    const float* __restrict__ W1, const float* __restrict__ b1,
    float* __restrict__ xa, float* __restrict__ yb)
{
    __shared__ float rows[4][128];
    const int bid = blockIdx.x;
    const int k = threadIdx.x;
    const bool is_x = bid < 256;
    const int r0 = (is_x ? bid : bid - 256) * 4;
    const float* src = (is_x ? x : y) + (size_t)r0 * 128;
    const float* w = is_x ? W1 : (W1 + 128 * 128);
#pragma unroll
    for (int r = 0; r < 4; ++r) rows[r][k] = src[r * 128 + k];
    __syncthreads();
    float acc[4];
    const float bias = is_x ? b1[k] : 0.0f;
#pragma unroll
    for (int r = 0; r < 4; ++r) acc[r] = bias;
    for (int d = 0; d < 128; ++d) {
        float wv = w[d * 128 + k];
#pragma unroll
        for (int r = 0; r < 4; ++r) acc[r] = fmaf(rows[r][d], wv, acc[r]);
    }
    float* dst = (is_x ? xa : yb) + (size_t)r0 * 128 + k;
#pragma unroll
    for (int r = 0; r < 4; ++r) dst[r * 128] = acc[r];
}

// Kernel 2: fused pairwise MLP. r12 structure (best measured): dual a-row ILP,
// W2a/y in registers, W3/b2 in LDS; b3 folded into layer-4 (r6-validated).
// Grid 512 x 256. a_chunk = bid>>3 (16 a's via LDS), wave b-group = (bid&7)*4+wave.
__global__ __launch_bounds__(256, 2) void fused_kernel(
    const float* __restrict__ xa, const float* __restrict__ yb,
    const float* __restrict__ W2, const float* __restrict__ b2,
    const float* __restrict__ W3, const float* __restrict__ b3,
    const float* __restrict__ W4, const float* __restrict__ b4,
    float* __restrict__ out)
{
    __shared__ float xa_lds[16 * 128];                      // 8 KB
    __shared__ __align__(16) short w3_lds[4 * 64 * 8];      // 4 KB: [s][lane][8]
    __shared__ __align__(64) float b2_lds[64];              // [mt][half][16] C-layout

    const int tid = threadIdx.x;
    const int bid = blockIdx.x;
    const int a_chunk = bid >> 3;        // 0..63, 16 a's each
    const int bq = bid & 7;
    const int wave = tid >> 6;
    const int lane = tid & 63;
    const int half = lane >> 5;
    const int m = lane & 31;
    const int bg = bq * 4 + wave;        // 0..31

    // ---- stage xa tile (16 rows x 128 f32): two f32x4 per thread ----
    {
        const f32x4* xsrc = (const f32x4*)(xa + (size_t)a_chunk * 16 * 128);
        f32x4* dst = (f32x4*)xa_lds;
        dst[tid] = xsrc[tid];
        dst[tid + 256] = xsrc[tid + 256];
    }
    // ---- W3 fragment table (M padded 8->32), r8-validated ----
    {
        int l = tid & 63, s = tid >> 6;
        int row = l & 31;
        int krow = s * 16 + (l >> 5) * 8;
        u32x4 q;
#pragma unroll
        for (int jj = 0; jj < 4; ++jj) {
            float lo = (row < 8) ? W3[(krow + 2 * jj) * 8 + row] : 0.f;
            float hi = (row < 8) ? W3[(krow + 2 * jj + 1) * 8 + row] : 0.f;
            q[jj] = cvtpk(lo, hi);
        }
        *(u32x4*)&w3_lds[tid * 8] = q;
    }
    // ---- b2 C-init table (r8-validated) ----
    if (tid < 64)
        b2_lds[tid] = b2[(tid & 3) + 8 * ((tid >> 2) & 3) + 4 * ((tid >> 4) & 1) + 32 * (tid >> 5)];

    // ---- y row in B-fragment order (r1/r5 slot mapping), registers ----
    f32x4 yv0[8], yv1[8];
    {
        const float* yrow = yb + (size_t)(bg * 32 + m) * 128 + half * 8;
#pragma unroll
        for (int s = 0; s < 8; ++s) {
            yv0[s] = *(const f32x4*)&yrow[s * 16];
            yv1[s] = *(const f32x4*)&yrow[s * 16 + 4];
        }
    }

    // Layer2 A = W2^T: A[m'][k], m' = lane&31 (+32*mt), k = s*16 + half*8 + j
    s16x8 W2a[2][8];
#pragma unroll
    for (int mt = 0; mt < 2; ++mt)
#pragma unroll
        for (int s = 0; s < 8; ++s)
#pragma unroll
            for (int j = 0; j < 8; ++j)
                W2a[mt][s][j] = f2bf(W2[(s * 16 + half * 8 + j) * 64 + mt * 32 + m]);

    const f32x16 fz = {};   // zero C for layer-3 chains (r6-validated)
    float b3v[4], w4v[4];
#pragma unroll
    for (int j = 0; j < 4; ++j) {
        b3v[j] = b3[j + 4 * half];
        w4v[j] = W4[j + 4 * half];
    }
    const float b4s = b4[0];

    __syncthreads();

    const short* w3p = &w3_lds[lane * 8];
    float* outp = out + (size_t)(a_chunk * 16) * 1024 + bg * 32 + m;

    for (int ai = 0; ai < 8; ++ai) {
        // ---- build layer-1 B-fragments for BOTH rows (ai and ai+8) ----
        s16x8 bfrA[8], bfrB[8];
        {
            const float* xrA = &xa_lds[ai * 128 + half * 8];
            const float* xrB = &xa_lds[(ai + 8) * 128 + half * 8];
#pragma unroll
            for (int s = 0; s < 8; ++s) {
                f32x4 a0 = *(const f32x4*)&xrA[s * 16] + yv0[s];
                f32x4 a1 = *(const f32x4*)&xrA[s * 16 + 4] + yv1[s];
                u32x4 qa;
                qa.x = cvtpk(fmaxf(a0.x, 0.f), fmaxf(a0.y, 0.f));
                qa.y = cvtpk(fmaxf(a0.z, 0.f), fmaxf(a0.w, 0.f));
                qa.z = cvtpk(fmaxf(a1.x, 0.f), fmaxf(a1.y, 0.f));
                qa.w = cvtpk(fmaxf(a1.z, 0.f), fmaxf(a1.w, 0.f));
                bfrA[s] = __builtin_bit_cast(s16x8, qa);
                f32x4 b0 = *(const f32x4*)&xrB[s * 16] + yv0[s];
                f32x4 b1 = *(const f32x4*)&xrB[s * 16 + 4] + yv1[s];
                u32x4 qb;
                qb.x = cvtpk(fmaxf(b0.x, 0.f), fmaxf(b0.y, 0.f));
                qb.y = cvtpk(fmaxf(b0.z, 0.f), fmaxf(b0.w, 0.f));
                qb.z = cvtpk(fmaxf(b1.x, 0.f), fmaxf(b1.y, 0.f));
                qb.w = cvtpk(fmaxf(b1.z, 0.f), fmaxf(b1.w, 0.f));
                bfrB[s] = __builtin_bit_cast(s16x8, qb);
            }
        }

        // ---- 4 independent L2 chains (b2 C-init from LDS, r8-validated) ----
        const f32x16 cb0 = *(const f32x16*)&b2_lds[half * 16];
        const f32x16 cb1 = *(const f32x16*)&b2_lds[32 + half * 16];
        f32x16 c20A = __builtin_amdgcn_mfma_f32_32x32x16_bf16(W2a[0][0], bfrA[0], cb0, 0, 0, 0);
        f32x16 c21A = __builtin_amdgcn_mfma_f32_32x32x16_bf16(W2a[1][0], bfrA[0], cb1, 0, 0, 0);
        f32x16 c20B = __builtin_amdgcn_mfma_f32_32x32x16_bf16(W2a[0][0], bfrB[0], cb0, 0, 0, 0);
        f32x16 c21B = __builtin_amdgcn_mfma_f32_32x32x16_bf16(W2a[1][0], bfrB[0], cb1, 0, 0, 0);
#pragma unroll
        for (int s = 1; s < 8; ++s) {
            c20A = __builtin_amdgcn_mfma_f32_32x32x16_bf16(W2a[0][s], bfrA[s], c20A, 0, 0, 0);
            c21A = __builtin_amdgcn_mfma_f32_32x32x16_bf16(W2a[1][s], bfrA[s], c21A, 0, 0, 0);
            c20B = __builtin_amdgcn_mfma_f32_32x32x16_bf16(W2a[0][s], bfrB[s], c20B, 0, 0, 0);
            c21B = __builtin_amdgcn_mfma_f32_32x32x16_bf16(W2a[1][s], bfrB[s], c21B, 0, 0, 0);
        }

        // ---- pack + swaps, row A then row B (validated r1/r3/r5) ----
        s16x8 bf3A[4], bf3B[4];
        {
            unsigned P[8], Q[8];
#pragma unroll
            for (int i = 0; i < 8; ++i) {
                P[i] = cvtpk(fmaxf(c20A[2 * i], 0.f), fmaxf(c20A[2 * i + 1], 0.f));
                Q[i] = cvtpk(fmaxf(c21A[2 * i], 0.f), fmaxf(c21A[2 * i + 1], 0.f));
            }
            unsigned w0 = P[0], w2 = P[2]; swap32(w0, w2);
            unsigned w1 = P[1], w3 = P[3]; swap32(w1, w3);
            u32x4 t; t.x = w0; t.y = w1; t.z = w2; t.w = w3;
            bf3A[0] = __builtin_bit_cast(s16x8, t);
            unsigned v0 = P[4], v2 = P[6]; swap32(v0, v2);
            unsigned v1 = P[5], v3 = P[7]; swap32(v1, v3);
            u32x4 u; u.x = v0; u.y = v1; u.z = v2; u.w = v3;
            bf3A[1] = __builtin_bit_cast(s16x8, u);
            unsigned a0 = Q[0], a2 = Q[2]; swap32(a0, a2);
            unsigned a1 = Q[1], a3 = Q[3]; swap32(a1, a3);
            u32x4 t2; t2.x = a0; t2.y = a1; t2.z = a2; t2.w = a3;
            bf3A[2] = __builtin_bit_cast(s16x8, t2);
            unsigned e0 = Q[4], e2 = Q[6]; swap32(e0, e2);
            unsigned e1 = Q[5], e3 = Q[7]; swap32(e1, e3);
            u32x4 u2; u2.x = e0; u2.y = e1; u2.z = e2; u2.w = e3;
            bf3A[3] = __builtin_bit_cast(s16x8, u2);
        }
        {
            unsigned P[8], Q[8];
#pragma unroll
            for (int i = 0; i < 8; ++i) {
                P[i] = cvtpk(fmaxf(c20B[2 * i], 0.f), fmaxf(c20B[2 * i + 1], 0.f));
                Q[i] = cvtpk(fmaxf(c21B[2 * i], 0.f), fmaxf(c21B[2 * i + 1], 0.f));
            }
            unsigned w0 = P[0], w2 = P[2]; swap32(w0, w2);
            unsigned w1 = P[1], w3 = P[3]; swap32(w1, w3);
            u32x4 t; t.x = w0; t.y = w1; t.z = w2; t.w = w3;
            bf3B[0] = __builtin_bit_cast(s16x8, t);
            unsigned v0 = P[4], v2 = P[6]; swap32(v0, v2);
            unsigned v1 = P[5], v3 = P[7]; swap32(v1, v3);
            u32x4 u; u.x = v0; u.y = v1; u.z = v2; u.w = v3;
            bf3B[1] = __builtin_bit_cast(s16x8, u);
            unsigned a0 = Q[0], a2 = Q[2]; swap32(a0, a2);
            unsigned a1 = Q[1], a3 = Q[3]; swap32(a1, a3);
            u32x4 t2; t2.x = a0; t2.y = a1; t2.z = a2; t2.w = a3;
            bf3B[2] = __builtin_bit_cast(s16x8, t2);
            unsigned e0 = Q[4], e2 = Q[6]; swap32(e0, e2);
            unsigned e1 = Q[5], e3 = Q[7]; swap32(e1, e3);
            u32x4 u2; u2.x = e0; u2.y = e1; u2.z = e2; u2.w = e3;
            bf3B[3] = __builtin_bit_cast(s16x8, u2);
        }

        // ---- 2 independent L3 chains (W3 frags from LDS, zero C-init) ----
        const s16x8 w3f0 = *(const s16x8*)(w3p + 0 * 512);
        const s16x8 w3f1 = *(const s16x8*)(w3p + 1 * 512);
        const s16x8 w3f2 = *(const s16x8*)(w3p + 2 * 512);
        const s16x8 w3f3 = *(const s16x8*)(w3p + 3 * 512);
        f32x16 c3A = __builtin_amdgcn_mfma_f32_32x32x16_bf16(w3f0, bf3A[0], fz, 0, 0, 0);
        f32x16 c3B = __builtin_amdgcn_mfma_f32_32x32x16_bf16(w3f0, bf3B[0], fz, 0, 0, 0);
        c3A = __builtin_amdgcn_mfma_f32_32x32x16_bf16(w3f1, bf3A[1], c3A, 0, 0, 0);
        c3B = __builtin_amdgcn_mfma_f32_32x32x16_bf16(w3f1, bf3B[1], c3B, 0, 0, 0);
        c3A = __builtin_amdgcn_mfma_f32_32x32x16_bf16(w3f2, bf3A[2], c3A, 0, 0, 0);
        c3B = __builtin_amdgcn_mfma_f32_32x32x16_bf16(w3f2, bf3B[2], c3B, 0, 0, 0);
        c3A = __builtin_amdgcn_mfma_f32_32x32x16_bf16(w3f3, bf3A[3], c3A, 0, 0, 0);
        c3B = __builtin_amdgcn_mfma_f32_32x32x16_bf16(w3f3, bf3B[3], c3B, 0, 0, 0);

        // ---- layer 4 (b3 folded, r6-validated) + cross-half combine + store ----
        float pA = 0.f, pB = 0.f;
#pragma unroll
        for (int j = 0; j < 4; ++j) {
            pA = fmaf(fmaxf(c3A[j] + b3v[j], 0.f), w4v[j], pA);
            pB = fmaf(fmaxf(c3B[j] + b3v[j], 0.f), w4v[j], pB);
        }
        unsigned puA = __builtin_bit_cast(unsigned, pA);
        unsigned pvA = puA;
        asm("" : "+v"(pvA));
        swap32(puA, pvA);
        unsigned puB = __builtin_bit_cast(unsigned, pB);
        unsigned pvB = puB;
        asm("" : "+v"(pvB));
        swap32(puB, pvB);
        float rA = __builtin_bit_cast(float, puA) + __builtin_bit_cast(float, pvA) + b4s;
        float rB = __builtin_bit_cast(float, puB) + __builtin_bit_cast(float, pvB) + b4s;
        if (half == 0) {
            outp[(size_t)ai * 1024] = rA;
            outp[(size_t)(ai + 8) * 1024] = rB;
        }
    }
}

extern "C" void kernel_launch(void* const* d_in, const int* in_sizes, int n_in,
                              void* d_out, int out_size, void* d_ws, size_t ws_size,
                              hipStream_t stream) {
    const float* x  = (const float*)d_in[0];
    const float* y  = (const float*)d_in[1];
    const float* W1 = (const float*)d_in[2];
    const float* b1 = (const float*)d_in[3];
    const float* W2 = (const float*)d_in[4];
    const float* b2 = (const float*)d_in[5];
    const float* W3 = (const float*)d_in[6];
    const float* b3 = (const float*)d_in[7];
    const float* W4 = (const float*)d_in[8];
    const float* b4 = (const float*)d_in[9];
    float* out = (float*)d_out;

    float* xa = (float*)d_ws;              // 1024*128 f32
    float* yb = xa + 1024 * 128;           // 1024*128 f32

    precompute_kernel<<<dim3(512), dim3(128), 0, stream>>>(x, y, W1, b1, xa, yb);
    fused_kernel<<<dim3(512), dim3(256), 0, stream>>>(xa, yb, W2, b2, W3, b3, W4, b4, out);
}

// Round 16
// 37.377 us; speedup vs baseline: 1.5544x; 1.0190x over previous
//
#include <hip/hip_runtime.h>
#include <hip/hip_bf16.h>

typedef float f32x4 __attribute__((ext_vector_type(4)));
typedef float f32x16 __attribute__((ext_vector_type(16)));
typedef short s16x8 __attribute__((ext_vector_type(8)));
typedef unsigned int u32x4 __attribute__((ext_vector_type(4)));

__device__ __forceinline__ short f2bf(float v) {
    __hip_bfloat16 h = __float2bfloat16(v);
    return __builtin_bit_cast(short, h);
}
__device__ __forceinline__ unsigned cvtpk(float lo, float hi) {
    unsigned r;
    asm("v_cvt_pk_bf16_f32 %0, %1, %2" : "=v"(r) : "v"(lo), "v"(hi));
    return r;
}
// v_permlane32_swap_b32: x <- {x_lo, y_lo}, y <- {x_hi, y_hi}
__device__ __forceinline__ void swap32(unsigned &x, unsigned &y) {
    asm("v_permlane32_swap_b32 %0, %1" : "+v"(x), "+v"(y));
}

// Kernel 1: xa[a][k] = b1[k] + sum_d x[a][d]*W1[d][k];  yb[b][k] = sum_d y[b][d]*W1[128+d][k]
// 512 blocks x 128 threads, 4 rows each (fills all CUs).
__global__ __launch_bounds__(128) void precompute_kernel(
    const float* __restrict__ x, const float* __restrict__ y,
    const float* __restrict__ W1, const float* __restrict__ b1,
    float* __restrict__ xa, float* __restrict__ yb)
{
    __shared__ float rows[4][128];
    const int bid = blockIdx.x;
    const int k = threadIdx.x;
    const bool is_x = bid < 256;
    const int r0 = (is_x ? bid : bid - 256) * 4;
    const float* src = (is_x ? x : y) + (size_t)r0 * 128;
    const float* w = is_x ? W1 : (W1 + 128 * 128);
#pragma unroll
    for (int r = 0; r < 4; ++r) rows[r][k] = src[r * 128 + k];
    __syncthreads();
    float acc[4];
    const float bias = is_x ? b1[k] : 0.0f;
#pragma unroll
    for (int r = 0; r < 4; ++r) acc[r] = bias;
    for (int d = 0; d < 128; ++d) {
        float wv = w[d * 128 + k];
#pragma unroll
        for (int r = 0; r < 4; ++r) acc[r] = fmaf(rows[r][d], wv, acc[r]);
    }
    float* dst = (is_x ? xa : yb) + (size_t)r0 * 128 + k;
#pragma unroll
    for (int r = 0; r < 4; ++r) dst[r * 128] = acc[r];
}

// Kernel 2: fused pairwise MLP. r15 structure (best measured) with the
// permlane-swap block ELIMINATED: the L3 B-fragments are the natural post-pack
// grouping bf3[t] = {P/Q[4t..4t+3]}, and the W3 LDS table is built with the
// matching k-permutation f = t*16 + (j>>2)*8 + half*4 + (j&3). MFMA is exact
// under a common k-relabeling of A and B (A/B share slot->k mapping, r1-proven).
// Grid 512 x 256. a_chunk = bid>>3 (16 a's via LDS), wave b-group = (bid&7)*4+wave.
__global__ __launch_bounds__(256, 2) void fused_kernel(
    const float* __restrict__ xa, const float* __restrict__ yb,
    const float* __restrict__ W2, const float* __restrict__ b2,
    const float* __restrict__ W3, const float* __restrict__ b3,
    const float* __restrict__ W4, const float* __restrict__ b4,
    float* __restrict__ out)
{
    __shared__ float xa_lds[16 * 128];                      // 8 KB
    __shared__ __align__(16) short w3_lds[4 * 64 * 8];      // 4 KB: [t][lane][8]
    __shared__ __align__(64) float b2_lds[64];              // [mt][half][16] C-layout

    const int tid = threadIdx.x;
    const int bid = blockIdx.x;
    const int a_chunk = bid >> 3;        // 0..63, 16 a's each
    const int bq = bid & 7;
    const int wave = tid >> 6;
    const int lane = tid & 63;
    const int half = lane >> 5;
    const int m = lane & 31;
    const int bg = bq * 4 + wave;        // 0..31

    // ---- stage xa tile (16 rows x 128 f32): two f32x4 per thread ----
    {
        const f32x4* xsrc = (const f32x4*)(xa + (size_t)a_chunk * 16 * 128);
        f32x4* dst = (f32x4*)xa_lds;
        dst[tid] = xsrc[tid];
        dst[tid + 256] = xsrc[tid + 256];
    }
    // ---- W3 fragment table, k-PERMUTED to the natural P/Q grouping:
    //      slot (t, half h, j) holds W3[f][row], f = t*16 + (j>>2)*8 + h*4 + (j&3)
    {
        int l = tid & 63, t = tid >> 6;
        int row = l & 31, h = l >> 5;
        u32x4 q;
#pragma unroll
        for (int jj = 0; jj < 4; ++jj) {
            int f = t * 16 + (jj >> 1) * 8 + h * 4 + ((2 * jj) & 3);
            float lo = (row < 8) ? W3[f * 8 + row] : 0.f;
            float hi = (row < 8) ? W3[(f + 1) * 8 + row] : 0.f;
            q[jj] = cvtpk(lo, hi);
        }
        *(u32x4*)&w3_lds[tid * 8] = q;
    }
    // ---- b2 C-init table (r8-validated) ----
    if (tid < 64)
        b2_lds[tid] = b2[(tid & 3) + 8 * ((tid >> 2) & 3) + 4 * ((tid >> 4) & 1) + 32 * (tid >> 5)];

    // ---- y row in B-fragment order (r1/r5 slot mapping), registers ----
    f32x4 yv0[8], yv1[8];
    {
        const float* yrow = yb + (size_t)(bg * 32 + m) * 128 + half * 8;
#pragma unroll
        for (int s = 0; s < 8; ++s) {
            yv0[s] = *(const f32x4*)&yrow[s * 16];
            yv1[s] = *(const f32x4*)&yrow[s * 16 + 4];
        }
    }

    // Layer2 A = W2^T: A[m'][k], m' = lane&31 (+32*mt), k = s*16 + half*8 + j
    s16x8 W2a[2][8];
#pragma unroll
    for (int mt = 0; mt < 2; ++mt)
#pragma unroll
        for (int s = 0; s < 8; ++s)
#pragma unroll
            for (int j = 0; j < 8; ++j)
                W2a[mt][s][j] = f2bf(W2[(s * 16 + half * 8 + j) * 64 + mt * 32 + m]);

    const f32x16 fz = {};   // zero C for layer-3 chains (r6-validated)
    float b3v[4], w4v[4];
#pragma unroll
    for (int j = 0; j < 4; ++j) {
        b3v[j] = b3[j + 4 * half];
        w4v[j] = W4[j + 4 * half];
    }
    const float b4s = b4[0];

    __syncthreads();

    const short* w3p = &w3_lds[lane * 8];
    float* outp = out + (size_t)(a_chunk * 16) * 1024 + bg * 32 + m;

    for (int ai = 0; ai < 8; ++ai) {
        // ---- build layer-1 B-fragments for BOTH rows (ai and ai+8) ----
        s16x8 bfrA[8], bfrB[8];
        {
            const float* xrA = &xa_lds[ai * 128 + half * 8];
            const float* xrB = &xa_lds[(ai + 8) * 128 + half * 8];
#pragma unroll
            for (int s = 0; s < 8; ++s) {
                f32x4 a0 = *(const f32x4*)&xrA[s * 16] + yv0[s];
                f32x4 a1 = *(const f32x4*)&xrA[s * 16 + 4] + yv1[s];
                u32x4 qa;
                qa.x = cvtpk(fmaxf(a0.x, 0.f), fmaxf(a0.y, 0.f));
                qa.y = cvtpk(fmaxf(a0.z, 0.f), fmaxf(a0.w, 0.f));
                qa.z = cvtpk(fmaxf(a1.x, 0.f), fmaxf(a1.y, 0.f));
                qa.w = cvtpk(fmaxf(a1.z, 0.f), fmaxf(a1.w, 0.f));
                bfrA[s] = __builtin_bit_cast(s16x8, qa);
                f32x4 b0 = *(const f32x4*)&xrB[s * 16] + yv0[s];
                f32x4 b1 = *(const f32x4*)&xrB[s * 16 + 4] + yv1[s];
                u32x4 qb;
                qb.x = cvtpk(fmaxf(b0.x, 0.f), fmaxf(b0.y, 0.f));
                qb.y = cvtpk(fmaxf(b0.z, 0.f), fmaxf(b0.w, 0.f));
                qb.z = cvtpk(fmaxf(b1.x, 0.f), fmaxf(b1.y, 0.f));
                qb.w = cvtpk(fmaxf(b1.z, 0.f), fmaxf(b1.w, 0.f));
                bfrB[s] = __builtin_bit_cast(s16x8, qb);
            }
        }

        // ---- 4 independent L2 chains (b2 C-init from LDS, r8-validated) ----
        const f32x16 cb0 = *(const f32x16*)&b2_lds[half * 16];
        const f32x16 cb1 = *(const f32x16*)&b2_lds[32 + half * 16];
        f32x16 c20A = __builtin_amdgcn_mfma_f32_32x32x16_bf16(W2a[0][0], bfrA[0], cb0, 0, 0, 0);
        f32x16 c21A = __builtin_amdgcn_mfma_f32_32x32x16_bf16(W2a[1][0], bfrA[0], cb1, 0, 0, 0);
        f32x16 c20B = __builtin_amdgcn_mfma_f32_32x32x16_bf16(W2a[0][0], bfrB[0], cb0, 0, 0, 0);
        f32x16 c21B = __builtin_amdgcn_mfma_f32_32x32x16_bf16(W2a[1][0], bfrB[0], cb1, 0, 0, 0);
#pragma unroll
        for (int s = 1; s < 8; ++s) {
            c20A = __builtin_amdgcn_mfma_f32_32x32x16_bf16(W2a[0][s], bfrA[s], c20A, 0, 0, 0);
            c21A = __builtin_amdgcn_mfma_f32_32x32x16_bf16(W2a[1][s], bfrA[s], c21A, 0, 0, 0);
            c20B = __builtin_amdgcn_mfma_f32_32x32x16_bf16(W2a[0][s], bfrB[s], c20B, 0, 0, 0);
            c21B = __builtin_amdgcn_mfma_f32_32x32x16_bf16(W2a[1][s], bfrB[s], c21B, 0, 0, 0);
        }

        // ---- pack (relu + bf16); natural grouping IS the L3 B-fragment now ----
        s16x8 bf3A[4], bf3B[4];
        {
            unsigned P[8], Q[8];
#pragma unroll
            for (int i = 0; i < 8; ++i) {
                P[i] = cvtpk(fmaxf(c20A[2 * i], 0.f), fmaxf(c20A[2 * i + 1], 0.f));
                Q[i] = cvtpk(fmaxf(c21A[2 * i], 0.f), fmaxf(c21A[2 * i + 1], 0.f));
            }
            u32x4 t0; t0.x = P[0]; t0.y = P[1]; t0.z = P[2]; t0.w = P[3];
            u32x4 t1; t1.x = P[4]; t1.y = P[5]; t1.z = P[6]; t1.w = P[7];
            u32x4 t2; t2.x = Q[0]; t2.y = Q[1]; t2.z = Q[2]; t2.w = Q[3];
            u32x4 t3; t3.x = Q[4]; t3.y = Q[5]; t3.z = Q[6]; t3.w = Q[7];
            bf3A[0] = __builtin_bit_cast(s16x8, t0);
            bf3A[1] = __builtin_bit_cast(s16x8, t1);
            bf3A[2] = __builtin_bit_cast(s16x8, t2);
            bf3A[3] = __builtin_bit_cast(s16x8, t3);
        }
        {
            unsigned P[8], Q[8];
#pragma unroll
            for (int i = 0; i < 8; ++i) {
                P[i] = cvtpk(fmaxf(c20B[2 * i], 0.f), fmaxf(c20B[2 * i + 1], 0.f));
                Q[i] = cvtpk(fmaxf(c21B[2 * i], 0.f), fmaxf(c21B[2 * i + 1], 0.f));
            }
            u32x4 t0; t0.x = P[0]; t0.y = P[1]; t0.z = P[2]; t0.w = P[3];
            u32x4 t1; t1.x = P[4]; t1.y = P[5]; t1.z = P[6]; t1.w = P[7];
            u32x4 t2; t2.x = Q[0]; t2.y = Q[1]; t2.z = Q[2]; t2.w = Q[3];
            u32x4 t3; t3.x = Q[4]; t3.y = Q[5]; t3.z = Q[6]; t3.w = Q[7];
            bf3B[0] = __builtin_bit_cast(s16x8, t0);
            bf3B[1] = __builtin_bit_cast(s16x8, t1);
            bf3B[2] = __builtin_bit_cast(s16x8, t2);
            bf3B[3] = __builtin_bit_cast(s16x8, t3);
        }

        // ---- 2 independent L3 chains (k-permuted W3 frags from LDS) ----
        const s16x8 w3f0 = *(const s16x8*)(w3p + 0 * 512);
        const s16x8 w3f1 = *(const s16x8*)(w3p + 1 * 512);
        const s16x8 w3f2 = *(const s16x8*)(w3p + 2 * 512);
        const s16x8 w3f3 = *(const s16x8*)(w3p + 3 * 512);
        f32x16 c3A = __builtin_amdgcn_mfma_f32_32x32x16_bf16(w3f0, bf3A[0], fz, 0, 0, 0);
        f32x16 c3B = __builtin_amdgcn_mfma_f32_32x32x16_bf16(w3f0, bf3B[0], fz, 0, 0, 0);
        c3A = __builtin_amdgcn_mfma_f32_32x32x16_bf16(w3f1, bf3A[1], c3A, 0, 0, 0);
        c3B = __builtin_amdgcn_mfma_f32_32x32x16_bf16(w3f1, bf3B[1], c3B, 0, 0, 0);
        c3A = __builtin_amdgcn_mfma_f32_32x32x16_bf16(w3f2, bf3A[2], c3A, 0, 0, 0);
        c3B = __builtin_amdgcn_mfma_f32_32x32x16_bf16(w3f2, bf3B[2], c3B, 0, 0, 0);
        c3A = __builtin_amdgcn_mfma_f32_32x32x16_bf16(w3f3, bf3A[3], c3A, 0, 0, 0);
        c3B = __builtin_amdgcn_mfma_f32_32x32x16_bf16(w3f3, bf3B[3], c3B, 0, 0, 0);

        // ---- layer 4 (b3 folded, r6-validated) + cross-half combine + store ----
        float pA = 0.f, pB = 0.f;
#pragma unroll
        for (int j = 0; j < 4; ++j) {
            pA = fmaf(fmaxf(c3A[j] + b3v[j], 0.f), w4v[j], pA);
            pB = fmaf(fmaxf(c3B[j] + b3v[j], 0.f), w4v[j], pB);
        }
        unsigned puA = __builtin_bit_cast(unsigned, pA);
        unsigned pvA = puA;
        asm("" : "+v"(pvA));
        swap32(puA, pvA);
        unsigned puB = __builtin_bit_cast(unsigned, pB);
        unsigned pvB = puB;
        asm("" : "+v"(pvB));
        swap32(puB, pvB);
        float rA = __builtin_bit_cast(float, puA) + __builtin_bit_cast(float, pvA) + b4s;
        float rB = __builtin_bit_cast(float, puB) + __builtin_bit_cast(float, pvB) + b4s;
        if (half == 0) {
            outp[(size_t)ai * 1024] = rA;
            outp[(size_t)(ai + 8) * 1024] = rB;
        }
    }
}

extern "C" void kernel_launch(void* const* d_in, const int* in_sizes, int n_in,
                              void* d_out, int out_size, void* d_ws, size_t ws_size,
                              hipStream_t stream) {
    const float* x  = (const float*)d_in[0];
    const float* y  = (const float*)d_in[1];
    const float* W1 = (const float*)d_in[2];
    const float* b1 = (const float*)d_in[3];
    const float* W2 = (const float*)d_in[4];
    const float* b2 = (const float*)d_in[5];
    const float* W3 = (const float*)d_in[6];
    const float* b3 = (const float*)d_in[7];
    const float* W4 = (const float*)d_in[8];
    const float* b4 = (const float*)d_in[9];
    float* out = (float*)d_out;

    float* xa = (float*)d_ws;              // 1024*128 f32
    float* yb = xa + 1024 * 128;           // 1024*128 f32

    precompute_kernel<<<dim3(512), dim3(128), 0, stream>>>(x, y, W1, b1, xa, yb);
    fused_kernel<<<dim3(512), dim3(256), 0, stream>>>(xa, yb, W2, b2, W3, b3, W4, b4, out);
}

// Round 18
// 37.308 us; speedup vs baseline: 1.5572x; 1.0018x over previous
//
#include <hip/hip_runtime.h>
#include <hip/hip_bf16.h>

typedef float f32x4 __attribute__((ext_vector_type(4)));
typedef float f32x16 __attribute__((ext_vector_type(16)));
typedef short s16x8 __attribute__((ext_vector_type(8)));
typedef unsigned int u32x4 __attribute__((ext_vector_type(4)));

__device__ __forceinline__ short f2bf(float v) {
    __hip_bfloat16 h = __float2bfloat16(v);
    return __builtin_bit_cast(short, h);
}
__device__ __forceinline__ unsigned cvtpk(float lo, float hi) {
    unsigned r;
    asm("v_cvt_pk_bf16_f32 %0, %1, %2" : "=v"(r) : "v"(lo), "v"(hi));
    return r;
}
// v_permlane32_swap_b32: x <- {x_lo, y_lo}, y <- {x_hi, y_hi}
__device__ __forceinline__ void swap32(unsigned &x, unsigned &y) {
    asm("v_permlane32_swap_b32 %0, %1" : "+v"(x), "+v"(y));
}

// Kernel 1: xa[a][k] = b1[k] + sum_d x[a][d]*W1[d][k];  yb[b][k] = sum_d y[b][d]*W1[128+d][k]
// 512 blocks x 128 threads, 4 rows each (fills all CUs).
__global__ __launch_bounds__(128) void precompute_kernel(
    const float* __restrict__ x, const float* __restrict__ y,
    const float* __restrict__ W1, const float* __restrict__ b1,
    float* __restrict__ xa, float* __restrict__ yb)
{
    __shared__ float rows[4][128];
    const int bid = blockIdx.x;
    const int k = threadIdx.x;
    const bool is_x = bid < 256;
    const int r0 = (is_x ? bid : bid - 256) * 4;
    const float* src = (is_x ? x : y) + (size_t)r0 * 128;
    const float* w = is_x ? W1 : (W1 + 128 * 128);
#pragma unroll
    for (int r = 0; r < 4; ++r) rows[r][k] = src[r * 128 + k];
    __syncthreads();
    float acc[4];
    const float bias = is_x ? b1[k] : 0.0f;
#pragma unroll
    for (int r = 0; r < 4; ++r) acc[r] = bias;
    for (int d = 0; d < 128; ++d) {
        float wv = w[d * 128 + k];
#pragma unroll
        for (int r = 0; r < 4; ++r) acc[r] = fmaf(rows[r][d], wv, acc[r]);
    }
    float* dst = (is_x ? xa : yb) + (size_t)r0 * 128 + k;
#pragma unroll
    for (int r = 0; r < 4; ++r) dst[r * 128] = acc[r];
}

// Kernel 2: fused pairwise MLP. Final configuration (r16, best measured):
// dual a-row ILP, W2a/y in registers, b2 C-init + k-permuted W3 table in LDS,
// swap-free L3 fragments, b3 folded into layer 4, f32 fmaxf relu (validated).
// Grid 512 x 256. a_chunk = bid>>3 (16 a's via LDS), wave b-group = (bid&7)*4+wave.
__global__ __launch_bounds__(256, 2) void fused_kernel(
    const float* __restrict__ xa, const float* __restrict__ yb,
    const float* __restrict__ W2, const float* __restrict__ b2,
    const float* __restrict__ W3, const float* __restrict__ b3,
    const float* __restrict__ W4, const float* __restrict__ b4,
    float* __restrict__ out)
{
    __shared__ float xa_lds[16 * 128];                      // 8 KB
    __shared__ __align__(16) short w3_lds[4 * 64 * 8];      // 4 KB: [t][lane][8]
    __shared__ __align__(64) float b2_lds[64];              // [mt][half][16] C-layout

    const int tid = threadIdx.x;
    const int bid = blockIdx.x;
    const int a_chunk = bid >> 3;        // 0..63, 16 a's each
    const int bq = bid & 7;
    const int wave = tid >> 6;
    const int lane = tid & 63;
    const int half = lane >> 5;
    const int m = lane & 31;
    const int bg = bq * 4 + wave;        // 0..31

    // ---- stage xa tile (16 rows x 128 f32): two f32x4 per thread ----
    {
        const f32x4* xsrc = (const f32x4*)(xa + (size_t)a_chunk * 16 * 128);
        f32x4* dst = (f32x4*)xa_lds;
        dst[tid] = xsrc[tid];
        dst[tid + 256] = xsrc[tid + 256];
    }
    // ---- W3 fragment table, k-PERMUTED to the natural P/Q grouping:
    //      slot (t, half h, j) holds W3[f][row], f = t*16 + (j>>2)*8 + h*4 + (j&3)
    {
        int l = tid & 63, t = tid >> 6;
        int row = l & 31, h = l >> 5;
        u32x4 q;
#pragma unroll
        for (int jj = 0; jj < 4; ++jj) {
            int f = t * 16 + (jj >> 1) * 8 + h * 4 + ((2 * jj) & 3);
            float lo = (row < 8) ? W3[f * 8 + row] : 0.f;
            float hi = (row < 8) ? W3[(f + 1) * 8 + row] : 0.f;
            q[jj] = cvtpk(lo, hi);
        }
        *(u32x4*)&w3_lds[tid * 8] = q;
    }
    // ---- b2 C-init table (r8-validated) ----
    if (tid < 64)
        b2_lds[tid] = b2[(tid & 3) + 8 * ((tid >> 2) & 3) + 4 * ((tid >> 4) & 1) + 32 * (tid >> 5)];

    // ---- y row in B-fragment order (r1/r5 slot mapping), registers ----
    f32x4 yv0[8], yv1[8];
    {
        const float* yrow = yb + (size_t)(bg * 32 + m) * 128 + half * 8;
#pragma unroll
        for (int s = 0; s < 8; ++s) {
            yv0[s] = *(const f32x4*)&yrow[s * 16];
            yv1[s] = *(const f32x4*)&yrow[s * 16 + 4];
        }
    }

    // Layer2 A = W2^T: A[m'][k], m' = lane&31 (+32*mt), k = s*16 + half*8 + j
    s16x8 W2a[2][8];
#pragma unroll
    for (int mt = 0; mt < 2; ++mt)
#pragma unroll
        for (int s = 0; s < 8; ++s)
#pragma unroll
            for (int j = 0; j < 8; ++j)
                W2a[mt][s][j] = f2bf(W2[(s * 16 + half * 8 + j) * 64 + mt * 32 + m]);

    const f32x16 fz = {};   // zero C for layer-3 chains (r6-validated)
    float b3v[4], w4v[4];
#pragma unroll
    for (int j = 0; j < 4; ++j) {
        b3v[j] = b3[j + 4 * half];
        w4v[j] = W4[j + 4 * half];
    }
    const float b4s = b4[0];

    __syncthreads();

    const short* w3p = &w3_lds[lane * 8];
    float* outp = out + (size_t)(a_chunk * 16) * 1024 + bg * 32 + m;

    for (int ai = 0; ai < 8; ++ai) {
        // ---- build layer-1 B-fragments for BOTH rows (ai and ai+8) ----
        s16x8 bfrA[8], bfrB[8];
        {
            const float* xrA = &xa_lds[ai * 128 + half * 8];
            const float* xrB = &xa_lds[(ai + 8) * 128 + half * 8];
#pragma unroll
            for (int s = 0; s < 8; ++s) {
                f32x4 a0 = *(const f32x4*)&xrA[s * 16] + yv0[s];
                f32x4 a1 = *(const f32x4*)&xrA[s * 16 + 4] + yv1[s];
                u32x4 qa;
                qa.x = cvtpk(fmaxf(a0.x, 0.f), fmaxf(a0.y, 0.f));
                qa.y = cvtpk(fmaxf(a0.z, 0.f), fmaxf(a0.w, 0.f));
                qa.z = cvtpk(fmaxf(a1.x, 0.f), fmaxf(a1.y, 0.f));
                qa.w = cvtpk(fmaxf(a1.z, 0.f), fmaxf(a1.w, 0.f));
                bfrA[s] = __builtin_bit_cast(s16x8, qa);
                f32x4 b0 = *(const f32x4*)&xrB[s * 16] + yv0[s];
                f32x4 b1 = *(const f32x4*)&xrB[s * 16 + 4] + yv1[s];
                u32x4 qb;
                qb.x = cvtpk(fmaxf(b0.x, 0.f), fmaxf(b0.y, 0.f));
                qb.y = cvtpk(fmaxf(b0.z, 0.f), fmaxf(b0.w, 0.f));
                qb.z = cvtpk(fmaxf(b1.x, 0.f), fmaxf(b1.y, 0.f));
                qb.w = cvtpk(fmaxf(b1.z, 0.f), fmaxf(b1.w, 0.f));
                bfrB[s] = __builtin_bit_cast(s16x8, qb);
            }
        }

        // ---- 4 independent L2 chains (b2 C-init from LDS, r8-validated) ----
        const f32x16 cb0 = *(const f32x16*)&b2_lds[half * 16];
        const f32x16 cb1 = *(const f32x16*)&b2_lds[32 + half * 16];
        f32x16 c20A = __builtin_amdgcn_mfma_f32_32x32x16_bf16(W2a[0][0], bfrA[0], cb0, 0, 0, 0);
        f32x16 c21A = __builtin_amdgcn_mfma_f32_32x32x16_bf16(W2a[1][0], bfrA[0], cb1, 0, 0, 0);
        f32x16 c20B = __builtin_amdgcn_mfma_f32_32x32x16_bf16(W2a[0][0], bfrB[0], cb0, 0, 0, 0);
        f32x16 c21B = __builtin_amdgcn_mfma_f32_32x32x16_bf16(W2a[1][0], bfrB[0], cb1, 0, 0, 0);
#pragma unroll
        for (int s = 1; s < 8; ++s) {
            c20A = __builtin_amdgcn_mfma_f32_32x32x16_bf16(W2a[0][s], bfrA[s], c20A, 0, 0, 0);
            c21A = __builtin_amdgcn_mfma_f32_32x32x16_bf16(W2a[1][s], bfrA[s], c21A, 0, 0, 0);
            c20B = __builtin_amdgcn_mfma_f32_32x32x16_bf16(W2a[0][s], bfrB[s], c20B, 0, 0, 0);
            c21B = __builtin_amdgcn_mfma_f32_32x32x16_bf16(W2a[1][s], bfrB[s], c21B, 0, 0, 0);
        }

        // ---- pack (relu + bf16); natural grouping IS the L3 B-fragment now ----
        s16x8 bf3A[4], bf3B[4];
        {
            unsigned P[8], Q[8];
#pragma unroll
            for (int i = 0; i < 8; ++i) {
                P[i] = cvtpk(fmaxf(c20A[2 * i], 0.f), fmaxf(c20A[2 * i + 1], 0.f));
                Q[i] = cvtpk(fmaxf(c21A[2 * i], 0.f), fmaxf(c21A[2 * i + 1], 0.f));
            }
            u32x4 t0; t0.x = P[0]; t0.y = P[1]; t0.z = P[2]; t0.w = P[3];
            u32x4 t1; t1.x = P[4]; t1.y = P[5]; t1.z = P[6]; t1.w = P[7];
            u32x4 t2; t2.x = Q[0]; t2.y = Q[1]; t2.z = Q[2]; t2.w = Q[3];
            u32x4 t3; t3.x = Q[4]; t3.y = Q[5]; t3.z = Q[6]; t3.w = Q[7];
            bf3A[0] = __builtin_bit_cast(s16x8, t0);
            bf3A[1] = __builtin_bit_cast(s16x8, t1);
            bf3A[2] = __builtin_bit_cast(s16x8, t2);
            bf3A[3] = __builtin_bit_cast(s16x8, t3);
        }
        {
            unsigned P[8], Q[8];
#pragma unroll
            for (int i = 0; i < 8; ++i) {
                P[i] = cvtpk(fmaxf(c20B[2 * i], 0.f), fmaxf(c20B[2 * i + 1], 0.f));
                Q[i] = cvtpk(fmaxf(c21B[2 * i], 0.f), fmaxf(c21B[2 * i + 1], 0.f));
            }
            u32x4 t0; t0.x = P[0]; t0.y = P[1]; t0.z = P[2]; t0.w = P[3];
            u32x4 t1; t1.x = P[4]; t1.y = P[5]; t1.z = P[6]; t1.w = P[7];
            u32x4 t2; t2.x = Q[0]; t2.y = Q[1]; t2.z = Q[2]; t2.w = Q[3];
            u32x4 t3; t3.x = Q[4]; t3.y = Q[5]; t3.z = Q[6]; t3.w = Q[7];
            bf3B[0] = __builtin_bit_cast(s16x8, t0);
            bf3B[1] = __builtin_bit_cast(s16x8, t1);
            bf3B[2] = __builtin_bit_cast(s16x8, t2);
            bf3B[3] = __builtin_bit_cast(s16x8, t3);
        }

        // ---- 2 independent L3 chains (k-permuted W3 frags from LDS) ----
        const s16x8 w3f0 = *(const s16x8*)(w3p + 0 * 512);
        const s16x8 w3f1 = *(const s16x8*)(w3p + 1 * 512);
        const s16x8 w3f2 = *(const s16x8*)(w3p + 2 * 512);
        const s16x8 w3f3 = *(const s16x8*)(w3p + 3 * 512);
        f32x16 c3A = __builtin_amdgcn_mfma_f32_32x32x16_bf16(w3f0, bf3A[0], fz, 0, 0, 0);
        f32x16 c3B = __builtin_amdgcn_mfma_f32_32x32x16_bf16(w3f0, bf3B[0], fz, 0, 0, 0);
        c3A = __builtin_amdgcn_mfma_f32_32x32x16_bf16(w3f1, bf3A[1], c3A, 0, 0, 0);
        c3B = __builtin_amdgcn_mfma_f32_32x32x16_bf16(w3f1, bf3B[1], c3B, 0, 0, 0);
        c3A = __builtin_amdgcn_mfma_f32_32x32x16_bf16(w3f2, bf3A[2], c3A, 0, 0, 0);
        c3B = __builtin_amdgcn_mfma_f32_32x32x16_bf16(w3f2, bf3B[2], c3B, 0, 0, 0);
        c3A = __builtin_amdgcn_mfma_f32_32x32x16_bf16(w3f3, bf3A[3], c3A, 0, 0, 0);
        c3B = __builtin_amdgcn_mfma_f32_32x32x16_bf16(w3f3, bf3B[3], c3B, 0, 0, 0);

        // ---- layer 4 (b3 folded, r6-validated) + cross-half combine + store ----
        float pA = 0.f, pB = 0.f;
#pragma unroll
        for (int j = 0; j < 4; ++j) {
            pA = fmaf(fmaxf(c3A[j] + b3v[j], 0.f), w4v[j], pA);
            pB = fmaf(fmaxf(c3B[j] + b3v[j], 0.f), w4v[j], pB);
        }
        unsigned puA = __builtin_bit_cast(unsigned, pA);
        unsigned pvA = puA;
        asm("" : "+v"(pvA));
        swap32(puA, pvA);
        unsigned puB = __builtin_bit_cast(unsigned, pB);
        unsigned pvB = puB;
        asm("" : "+v"(pvB));
        swap32(puB, pvB);
        float rA = __builtin_bit_cast(float, puA) + __builtin_bit_cast(float, pvA) + b4s;
        float rB = __builtin_bit_cast(float, puB) + __builtin_bit_cast(float, pvB) + b4s;
        if (half == 0) {
            outp[(size_t)ai * 1024] = rA;
            outp[(size_t)(ai + 8) * 1024] = rB;
        }
    }
}

extern "C" void kernel_launch(void* const* d_in, const int* in_sizes, int n_in,
                              void* d_out, int out_size, void* d_ws, size_t ws_size,
                              hipStream_t stream) {
    const float* x  = (const float*)d_in[0];
    const float* y  = (const float*)d_in[1];
    const float* W1 = (const float*)d_in[2];
    const float* b1 = (const float*)d_in[3];
    const float* W2 = (const float*)d_in[4];
    const float* b2 = (const float*)d_in[5];
    const float* W3 = (const float*)d_in[6];
    const float* b3 = (const float*)d_in[7];
    const float* W4 = (const float*)d_in[8];
    const float* b4 = (const float*)d_in[9];
    float* out = (float*)d_out;

    float* xa = (float*)d_ws;              // 1024*128 f32
    float* yb = xa + 1024 * 128;           // 1024*128 f32

    precompute_kernel<<<dim3(512), dim3(128), 0, stream>>>(x, y, W1, b1, xa, yb);
    fused_kernel<<<dim3(512), dim3(256), 0, stream>>>(xa, yb, W2, b2, W3, b3, W4, b4, out);
}